// Round 1
// baseline (566.130 us; speedup 1.0000x reference)
//
#include <hip/hip_runtime.h>
#include <hip/hip_bf16.h>

typedef __attribute__((ext_vector_type(4))) float f32x4;
typedef __attribute__((ext_vector_type(8))) short short8;

#define DEV __device__ __forceinline__

DEV short f2bf(float f) {
    union { float f; unsigned u; } a; a.f = f;
    unsigned r = a.u + 0x7fffu + ((a.u >> 16) & 1u);
    return (short)(r >> 16);
}

DEV float gelu_f(float x) {
    // jax.nn.gelu approximate=True (tanh form)
    float u = 0.7978845608028654f * (x + 0.044715f * x * x * x);
    float e = __expf(2.0f * u);
    float t = 1.0f - 2.0f / (e + 1.0f);   // tanh(u)
    return 0.5f * x * (1.0f + t);
}

// ---------------- LayerNorm: fp32 in -> bf16 out, D=512, wave per row ----------------
__global__ __launch_bounds__(256) void ln_kernel(const float* __restrict__ x,
                                                 const float* __restrict__ scale,
                                                 const float* __restrict__ offset,
                                                 short* __restrict__ out) {
    const int wid = threadIdx.x >> 6, lane = threadIdx.x & 63;
    const long row = (long)blockIdx.x * 4 + wid;
    const float* xr = x + row * 512;
    f32x4 v0 = *(const f32x4*)&xr[lane * 8];
    f32x4 v1 = *(const f32x4*)&xr[lane * 8 + 4];
    float s = 0.f, sq = 0.f;
#pragma unroll
    for (int i = 0; i < 4; i++) {
        s += v0[i] + v1[i];
        sq += v0[i] * v0[i] + v1[i] * v1[i];
    }
#pragma unroll
    for (int m = 1; m < 64; m <<= 1) { s += __shfl_xor(s, m); sq += __shfl_xor(sq, m); }
    float mean = s * (1.0f / 512.0f);
    float var = sq * (1.0f / 512.0f) - mean * mean;
    float inv = rsqrtf(var + 1e-5f);
    f32x4 sc0 = *(const f32x4*)&scale[lane * 8];
    f32x4 sc1 = *(const f32x4*)&scale[lane * 8 + 4];
    f32x4 of0 = *(const f32x4*)&offset[lane * 8];
    f32x4 of1 = *(const f32x4*)&offset[lane * 8 + 4];
    short8 o;
#pragma unroll
    for (int i = 0; i < 4; i++) {
        o[i]     = f2bf((v0[i] - mean) * inv * sc0[i] + of0[i]);
        o[4 + i] = f2bf((v1[i] - mean) * inv * sc1[i] + of1[i]);
    }
    *(short8*)&out[row * 512 + lane * 8] = o;
}

// ---------------- Weight convert+transpose: w[K][N] fp32 -> wt[N][K] bf16 ----------------
__global__ __launch_bounds__(256) void wconv_t(const float* __restrict__ w,
                                               short* __restrict__ wt, int Kd, int N) {
    __shared__ float tile[64][65];
    const int k0 = blockIdx.x * 64, n0 = blockIdx.y * 64;
    const int tid = threadIdx.x;
#pragma unroll
    for (int ld = 0; ld < 4; ld++) {
        int li = ld * 1024 + tid * 4;
        int r = li >> 6, c = li & 63;
        f32x4 tv = *(const f32x4*)&w[(long)(k0 + r) * N + n0 + c];
        tile[r][c] = tv[0]; tile[r][c + 1] = tv[1];
        tile[r][c + 2] = tv[2]; tile[r][c + 3] = tv[3];
    }
    __syncthreads();
#pragma unroll
    for (int st = 0; st < 2; st++) {
        int li = st * 2048 + tid * 8;
        int r = li >> 6, c = li & 63;   // r: n-offset, c: k-offset
        short8 o;
#pragma unroll
        for (int i = 0; i < 8; i++) o[i] = f2bf(tile[c + i][r]);
        *(short8*)&wt[(long)(n0 + r) * Kd + k0 + c] = o;
    }
}

// ---------------- GEMM: C[M][N] = A[M][Kd] @ Bt[N][Kd]^T + bias (+gelu)(+resid) ----------------
// 128x128 tile, BK=64, 4 waves (2x2), each wave 64x64 via 4x4 mfma_f32_16x16x32_bf16
template <bool GELU_ACT, bool OUT_BF16, bool RESID>
__global__ __launch_bounds__(256) void gemm_bt(const short* __restrict__ A,
                                               const short* __restrict__ Bt,
                                               const float* __restrict__ bias,
                                               const float* __restrict__ resid,
                                               void* __restrict__ Cout,
                                               int M, int N, int Kd) {
    __shared__ short Asm[128][72];
    __shared__ short Bsm[128][72];
    const int tid = threadIdx.x;
    const int wid = tid >> 6, lane = tid & 63;
    const int lr = lane & 15, lg = lane >> 4;
    const int row0 = blockIdx.x * 128, col0 = blockIdx.y * 128;
    const int wm = (wid >> 1) * 64, wn = (wid & 1) * 64;

    f32x4 acc[4][4];
#pragma unroll
    for (int m = 0; m < 4; m++)
#pragma unroll
        for (int n = 0; n < 4; n++)
#pragma unroll
            for (int j = 0; j < 4; j++) acc[m][n][j] = 0.f;

    for (int k0 = 0; k0 < Kd; k0 += 64) {
#pragma unroll
        for (int ld = 0; ld < 4; ld++) {
            int li = ld * 2048 + tid * 8;
            int r = li >> 6, c = li & 63;
            *(short8*)&Asm[r][c] = *(const short8*)&A[(long)(row0 + r) * Kd + k0 + c];
            *(short8*)&Bsm[r][c] = *(const short8*)&Bt[(long)(col0 + r) * Kd + k0 + c];
        }
        __syncthreads();
#pragma unroll
        for (int kk = 0; kk < 64; kk += 32) {
            short8 af[4], bf[4];
#pragma unroll
            for (int m = 0; m < 4; m++) af[m] = *(const short8*)&Asm[wm + m * 16 + lr][kk + lg * 8];
#pragma unroll
            for (int n = 0; n < 4; n++) bf[n] = *(const short8*)&Bsm[wn + n * 16 + lr][kk + lg * 8];
#pragma unroll
            for (int m = 0; m < 4; m++)
#pragma unroll
                for (int n = 0; n < 4; n++)
                    acc[m][n] = __builtin_amdgcn_mfma_f32_16x16x32_bf16(af[m], bf[n], acc[m][n], 0, 0, 0);
        }
        __syncthreads();
    }

#pragma unroll
    for (int m = 0; m < 4; m++) {
#pragma unroll
        for (int n = 0; n < 4; n++) {
#pragma unroll
            for (int j = 0; j < 4; j++) {
                int r = row0 + wm + m * 16 + lg * 4 + j;
                int c = col0 + wn + n * 16 + lr;
                float v = acc[m][n][j] + bias[c];
                if constexpr (GELU_ACT) v = gelu_f(v);
                if constexpr (RESID) v += resid[(long)r * N + c];
                if constexpr (OUT_BF16) ((short*)Cout)[(long)r * N + c] = f2bf(v);
                else                    ((float*)Cout)[(long)r * N + c] = v;
            }
        }
    }
}

// ---------------- Flash attention: bf16 q,k,v (B,T,H*K) -> bf16 ctx ----------------
// Block: 64 Q rows of one (b,h); 4 waves x 16 rows. KV tiles of 64.
__global__ __launch_bounds__(256) void attn_kernel(const short* __restrict__ q,
                                                   const short* __restrict__ k,
                                                   const short* __restrict__ v,
                                                   short* __restrict__ ctx) {
    __shared__ short Ksm[64][72];        // [key][d]
    __shared__ short Vsm[64][72];        // [d][key]  (transposed)
    __shared__ short Psm[4][16][72];     // per-wave P staging
    const int tid = threadIdx.x, wid = tid >> 6, lane = tid & 63;
    const int lr = lane & 15, lg = lane >> 4;
    const int bh = blockIdx.y, b = bh >> 3, h = bh & 7;
    const int t0 = blockIdx.x * 64;
    const long base = (long)b * 4096 * 512 + h * 64;

    short8 qf[2];
    {
        const long qoff = base + (long)(t0 + wid * 16 + lr) * 512;
        qf[0] = *(const short8*)&q[qoff + lg * 8];
        qf[1] = *(const short8*)&q[qoff + 32 + lg * 8];
    }
    f32x4 o[4];
    float mrow[4], lrow[4];
#pragma unroll
    for (int n = 0; n < 4; n++)
#pragma unroll
        for (int j = 0; j < 4; j++) o[n][j] = 0.f;
#pragma unroll
    for (int j = 0; j < 4; j++) { mrow[j] = -1e30f; lrow[j] = 0.f; }

    for (int s0 = 0; s0 < 4096; s0 += 64) {
#pragma unroll
        for (int ld = 0; ld < 2; ld++) {
            int li = ld * 2048 + tid * 8;
            int key = li >> 6, d = li & 63;
            const long koff = base + (long)(s0 + key) * 512 + d;
            *(short8*)&Ksm[key][d] = *(const short8*)&k[koff];
            short8 vv = *(const short8*)&v[koff];
#pragma unroll
            for (int i = 0; i < 8; i++) Vsm[d + i][key] = vv[i];
        }
        __syncthreads();

        f32x4 s[4];
#pragma unroll
        for (int c = 0; c < 4; c++) {
#pragma unroll
            for (int j = 0; j < 4; j++) s[c][j] = 0.f;
#pragma unroll
            for (int kk = 0; kk < 2; kk++) {
                short8 kf = *(const short8*)&Ksm[c * 16 + lr][kk * 32 + lg * 8];
                s[c] = __builtin_amdgcn_mfma_f32_16x16x32_bf16(qf[kk], kf, s[c], 0, 0, 0);
            }
        }
        // online softmax per q-row (row = lg*4+j; reduce across the 16 lanes of lr)
#pragma unroll
        for (int j = 0; j < 4; j++) {
            float sj0 = s[0][j] * 0.125f, sj1 = s[1][j] * 0.125f;
            float sj2 = s[2][j] * 0.125f, sj3 = s[3][j] * 0.125f;
            float mx = fmaxf(fmaxf(sj0, sj1), fmaxf(sj2, sj3));
            mx = fmaxf(mx, __shfl_xor(mx, 1));
            mx = fmaxf(mx, __shfl_xor(mx, 2));
            mx = fmaxf(mx, __shfl_xor(mx, 4));
            mx = fmaxf(mx, __shfl_xor(mx, 8));
            float mn = fmaxf(mrow[j], mx);
            float alpha = __expf(mrow[j] - mn);
            mrow[j] = mn;
            sj0 = __expf(sj0 - mn); sj1 = __expf(sj1 - mn);
            sj2 = __expf(sj2 - mn); sj3 = __expf(sj3 - mn);
            float rs = sj0 + sj1 + sj2 + sj3;
            rs += __shfl_xor(rs, 1);
            rs += __shfl_xor(rs, 2);
            rs += __shfl_xor(rs, 4);
            rs += __shfl_xor(rs, 8);
            lrow[j] = lrow[j] * alpha + rs;
#pragma unroll
            for (int n = 0; n < 4; n++) o[n][j] *= alpha;
            s[0][j] = sj0; s[1][j] = sj1; s[2][j] = sj2; s[3][j] = sj3;
        }
        // P: C-layout -> A-layout via per-wave LDS round trip
#pragma unroll
        for (int c = 0; c < 4; c++)
#pragma unroll
            for (int j = 0; j < 4; j++)
                Psm[wid][lg * 4 + j][c * 16 + lr] = f2bf(s[c][j]);
        short8 pa0 = *(const short8*)&Psm[wid][lr][lg * 8];
        short8 pa1 = *(const short8*)&Psm[wid][lr][32 + lg * 8];
#pragma unroll
        for (int n = 0; n < 4; n++) {
            short8 vf0 = *(const short8*)&Vsm[n * 16 + lr][lg * 8];
            short8 vf1 = *(const short8*)&Vsm[n * 16 + lr][32 + lg * 8];
            o[n] = __builtin_amdgcn_mfma_f32_16x16x32_bf16(pa0, vf0, o[n], 0, 0, 0);
            o[n] = __builtin_amdgcn_mfma_f32_16x16x32_bf16(pa1, vf1, o[n], 0, 0, 0);
        }
        __syncthreads();
    }

    const long obase = base + (long)(t0 + wid * 16) * 512;
#pragma unroll
    for (int n = 0; n < 4; n++)
#pragma unroll
        for (int j = 0; j < 4; j++)
            ctx[obase + (long)(lg * 4 + j) * 512 + n * 16 + lr] = f2bf(o[n][j] / lrow[j]);
}

// ---------------- Orchestration ----------------
extern "C" void kernel_launch(void* const* d_in, const int* in_sizes, int n_in,
                              void* d_out, int out_size, void* d_ws, size_t ws_size,
                              hipStream_t stream) {
    (void)in_sizes; (void)n_in; (void)out_size; (void)ws_size;
    const float* inputs = (const float*)d_in[0];
    const float* ln1_s  = (const float*)d_in[1];
    const float* ln1_o  = (const float*)d_in[2];
    const float* wq     = (const float*)d_in[3];
    const float* bq     = (const float*)d_in[4];
    const float* wk     = (const float*)d_in[5];
    const float* bk     = (const float*)d_in[6];
    const float* wv     = (const float*)d_in[7];
    const float* bv     = (const float*)d_in[8];
    const float* wo     = (const float*)d_in[9];
    const float* bo     = (const float*)d_in[10];
    const float* ln2_s  = (const float*)d_in[11];
    const float* ln2_o  = (const float*)d_in[12];
    const float* w1     = (const float*)d_in[13];
    const float* b1     = (const float*)d_in[14];
    const float* w2     = (const float*)d_in[15];
    const float* b2     = (const float*)d_in[16];
    float* out = (float*)d_out;

    char* p = (char*)d_ws;
    auto alloc = [&](size_t bytes) { void* r = (void*)p; p += (bytes + 255) & ~(size_t)255; return r; };
    short* x1   = (short*)alloc((size_t)8192 * 512 * 2);
    short* qb   = (short*)alloc((size_t)8192 * 512 * 2);
    short* kb   = (short*)alloc((size_t)8192 * 512 * 2);
    short* vb   = (short*)alloc((size_t)8192 * 512 * 2);
    short* ctxb = (short*)alloc((size_t)8192 * 512 * 2);
    short* yb   = (short*)alloc((size_t)8192 * 512 * 2);
    short* hb   = (short*)alloc((size_t)8192 * 2048 * 2);
    short* wqt  = (short*)alloc((size_t)512 * 512 * 2);
    short* wkt  = (short*)alloc((size_t)512 * 512 * 2);
    short* wvt  = (short*)alloc((size_t)512 * 512 * 2);
    short* wot  = (short*)alloc((size_t)512 * 512 * 2);
    short* w1t  = (short*)alloc((size_t)2048 * 512 * 2);
    short* w2t  = (short*)alloc((size_t)512 * 2048 * 2);

    dim3 blk(256);
    // weights -> bf16 transposed
    wconv_t<<<dim3(8, 8), blk, 0, stream>>>(wq, wqt, 512, 512);
    wconv_t<<<dim3(8, 8), blk, 0, stream>>>(wk, wkt, 512, 512);
    wconv_t<<<dim3(8, 8), blk, 0, stream>>>(wv, wvt, 512, 512);
    wconv_t<<<dim3(8, 8), blk, 0, stream>>>(wo, wot, 512, 512);
    wconv_t<<<dim3(8, 32), blk, 0, stream>>>(w1, w1t, 512, 2048);
    wconv_t<<<dim3(32, 8), blk, 0, stream>>>(w2, w2t, 2048, 512);

    // LN1
    ln_kernel<<<2048, blk, 0, stream>>>(inputs, ln1_s, ln1_o, x1);
    // QKV
    gemm_bt<false, true, false><<<dim3(64, 4), blk, 0, stream>>>(x1, wqt, bq, nullptr, qb, 8192, 512, 512);
    gemm_bt<false, true, false><<<dim3(64, 4), blk, 0, stream>>>(x1, wkt, bk, nullptr, kb, 8192, 512, 512);
    gemm_bt<false, true, false><<<dim3(64, 4), blk, 0, stream>>>(x1, wvt, bv, nullptr, vb, 8192, 512, 512);
    // attention
    attn_kernel<<<dim3(64, 16), blk, 0, stream>>>(qb, kb, vb, ctxb);
    // out-proj + residual -> x (in d_out, fp32)
    gemm_bt<false, false, true><<<dim3(64, 4), blk, 0, stream>>>(ctxb, wot, bo, inputs, out, 8192, 512, 512);
    // LN2
    ln_kernel<<<2048, blk, 0, stream>>>(out, ln2_s, ln2_o, yb);
    // FFN1 + GELU
    gemm_bt<true, true, false><<<dim3(64, 16), blk, 0, stream>>>(yb, w1t, b1, nullptr, hb, 8192, 2048, 512);
    // FFN2 + residual -> out
    gemm_bt<false, false, true><<<dim3(64, 4), blk, 0, stream>>>(hb, w2t, b2, out, out, 8192, 512, 2048);
}

// Round 3
// 435.651 us; speedup vs baseline: 1.2995x; 1.2995x over previous
//
#include <hip/hip_runtime.h>
#include <hip/hip_bf16.h>

typedef __attribute__((ext_vector_type(4))) float f32x4;
typedef __attribute__((ext_vector_type(8))) short short8;

#define DEV __device__ __forceinline__

DEV short f2bf(float f) {
    union { float f; unsigned u; } a; a.f = f;
    unsigned r = a.u + 0x7fffu + ((a.u >> 16) & 1u);
    return (short)(r >> 16);
}

DEV float bf2f(short s) {
    union { unsigned u; float f; } a;
    a.u = ((unsigned)(unsigned short)s) << 16;
    return a.f;
}

DEV float gelu_f(float x) {
    float u = 0.7978845608028654f * (x + 0.044715f * x * x * x);
    float e = __expf(2.0f * u);
    float t = 1.0f - 2.0f / (e + 1.0f);   // tanh(u)
    return 0.5f * x * (1.0f + t);
}

// ---------------- LayerNorm: fp32 in -> bf16 out, D=512, wave per row ----------------
__global__ __launch_bounds__(256) void ln_kernel(const float* __restrict__ x,
                                                 const float* __restrict__ scale,
                                                 const float* __restrict__ offset,
                                                 short* __restrict__ out) {
    const int wid = threadIdx.x >> 6, lane = threadIdx.x & 63;
    const long row = (long)blockIdx.x * 4 + wid;
    const float* xr = x + row * 512;
    f32x4 v0 = *(const f32x4*)&xr[lane * 8];
    f32x4 v1 = *(const f32x4*)&xr[lane * 8 + 4];
    float s = 0.f, sq = 0.f;
#pragma unroll
    for (int i = 0; i < 4; i++) {
        s += v0[i] + v1[i];
        sq += v0[i] * v0[i] + v1[i] * v1[i];
    }
#pragma unroll
    for (int m = 1; m < 64; m <<= 1) { s += __shfl_xor(s, m); sq += __shfl_xor(sq, m); }
    float mean = s * (1.0f / 512.0f);
    float var = sq * (1.0f / 512.0f) - mean * mean;
    float inv = rsqrtf(var + 1e-5f);
    f32x4 sc0 = *(const f32x4*)&scale[lane * 8];
    f32x4 sc1 = *(const f32x4*)&scale[lane * 8 + 4];
    f32x4 of0 = *(const f32x4*)&offset[lane * 8];
    f32x4 of1 = *(const f32x4*)&offset[lane * 8 + 4];
    short8 o;
#pragma unroll
    for (int i = 0; i < 4; i++) {
        o[i]     = f2bf((v0[i] - mean) * inv * sc0[i] + of0[i]);
        o[4 + i] = f2bf((v1[i] - mean) * inv * sc1[i] + of1[i]);
    }
    *(short8*)&out[row * 512 + lane * 8] = o;
}

// ---------------- Weight convert+transpose: w[K][N] fp32 -> wt[N][K] bf16 ----------------
__global__ __launch_bounds__(256) void wconv_t(const float* __restrict__ w,
                                               short* __restrict__ wt, int Kd, int N) {
    __shared__ float tile[64][65];
    const int k0 = blockIdx.x * 64, n0 = blockIdx.y * 64;
    const int tid = threadIdx.x;
#pragma unroll
    for (int ld = 0; ld < 4; ld++) {
        int li = ld * 1024 + tid * 4;
        int r = li >> 6, c = li & 63;
        f32x4 tv = *(const f32x4*)&w[(long)(k0 + r) * N + n0 + c];
        tile[r][c] = tv[0]; tile[r][c + 1] = tv[1];
        tile[r][c + 2] = tv[2]; tile[r][c + 3] = tv[3];
    }
    __syncthreads();
#pragma unroll
    for (int st = 0; st < 2; st++) {
        int li = st * 2048 + tid * 8;
        int r = li >> 6, c = li & 63;   // r: n-offset, c: k-offset
        short8 o;
#pragma unroll
        for (int i = 0; i < 8; i++) o[i] = f2bf(tile[c + i][r]);
        *(short8*)&wt[(long)(n0 + r) * Kd + k0 + c] = o;
    }
}

// ---------------- GEMM: C[M][N] = A[M][Kd] @ Bt[N][Kd]^T + bias (+gelu)(+resid) ----------------
template <bool GELU_ACT, bool OUT_BF16, bool RESID>
__global__ __launch_bounds__(256) void gemm_bt(const short* __restrict__ A,
                                               const short* __restrict__ Bt,
                                               const float* __restrict__ bias,
                                               const float* __restrict__ resid,
                                               void* __restrict__ Cout,
                                               int M, int N, int Kd) {
    __shared__ short Asm[128][72];
    __shared__ short Bsm[128][72];
    const int tid = threadIdx.x;
    const int wid = tid >> 6, lane = tid & 63;
    const int lr = lane & 15, lg = lane >> 4;
    const int row0 = blockIdx.x * 128, col0 = blockIdx.y * 128;
    const int wm = (wid >> 1) * 64, wn = (wid & 1) * 64;

    f32x4 acc[4][4];
#pragma unroll
    for (int m = 0; m < 4; m++)
#pragma unroll
        for (int n = 0; n < 4; n++)
#pragma unroll
            for (int j = 0; j < 4; j++) acc[m][n][j] = 0.f;

    for (int k0 = 0; k0 < Kd; k0 += 64) {
#pragma unroll
        for (int ld = 0; ld < 4; ld++) {
            int li = ld * 2048 + tid * 8;
            int r = li >> 6, c = li & 63;
            *(short8*)&Asm[r][c] = *(const short8*)&A[(long)(row0 + r) * Kd + k0 + c];
            *(short8*)&Bsm[r][c] = *(const short8*)&Bt[(long)(col0 + r) * Kd + k0 + c];
        }
        __syncthreads();
#pragma unroll
        for (int kk = 0; kk < 64; kk += 32) {
            short8 af[4], bf[4];
#pragma unroll
            for (int m = 0; m < 4; m++) af[m] = *(const short8*)&Asm[wm + m * 16 + lr][kk + lg * 8];
#pragma unroll
            for (int n = 0; n < 4; n++) bf[n] = *(const short8*)&Bsm[wn + n * 16 + lr][kk + lg * 8];
#pragma unroll
            for (int m = 0; m < 4; m++)
#pragma unroll
                for (int n = 0; n < 4; n++)
                    acc[m][n] = __builtin_amdgcn_mfma_f32_16x16x32_bf16(af[m], bf[n], acc[m][n], 0, 0, 0);
        }
        __syncthreads();
    }

#pragma unroll
    for (int m = 0; m < 4; m++) {
#pragma unroll
        for (int n = 0; n < 4; n++) {
#pragma unroll
            for (int j = 0; j < 4; j++) {
                int r = row0 + wm + m * 16 + lg * 4 + j;
                int c = col0 + wn + n * 16 + lr;
                float v = acc[m][n][j] + bias[c];
                if constexpr (GELU_ACT) v = gelu_f(v);
                if constexpr (RESID) v += resid[(long)r * N + c];
                if constexpr (OUT_BF16) ((short*)Cout)[(long)r * N + c] = f2bf(v);
                else                    ((float*)Cout)[(long)r * N + c] = v;
            }
        }
    }
}

// ---------------- Flash attention v2 ----------------
// q,k,v point into fused QKV buffer [8192][1536] (bf16), row stride 1536.
// Block: 64 Q rows of one (b,h); 4 waves x 16 rows. KV tiles of 128.
// Vsm stored transposed [d][key] with XOR swizzle (key ^ ((row>>3)<<3)) ->
// conflict-free scalar writes (was the 7.76e7-conflict hotspot).
__global__ __launch_bounds__(256) void attn_kernel(const short* __restrict__ q,
                                                   const short* __restrict__ k,
                                                   const short* __restrict__ v,
                                                   short* __restrict__ ctx) {
    __shared__ short Ksm[128][72];       // [key][d]
    __shared__ short Vsm[64][136];       // [d][key^swz]
    __shared__ short Psm[4][16][136];    // per-wave P staging [qrow][key]
    const int tid = threadIdx.x, wid = tid >> 6, lane = tid & 63;
    const int lr = lane & 15, lg = lane >> 4;
    const int bh = blockIdx.y, b = bh >> 3, h = bh & 7;
    const int t0 = blockIdx.x * 64;
    const long base = (long)b * 4096 * 1536 + h * 64;

    short8 qf[2];
    {
        const long qoff = base + (long)(t0 + wid * 16 + lr) * 1536 + lg * 8;
        qf[0] = *(const short8*)&q[qoff];
        qf[1] = *(const short8*)&q[qoff + 32];
        // pre-scale Q by 1/sqrt(64)=0.125 (power of 2: exact in bf16)
#pragma unroll
        for (int hh = 0; hh < 2; hh++)
#pragma unroll
            for (int i = 0; i < 8; i++)
                qf[hh][i] = f2bf(bf2f(qf[hh][i]) * 0.125f);
    }

    f32x4 o[4];
    float mrow[4], lrow[4];
#pragma unroll
    for (int n = 0; n < 4; n++)
#pragma unroll
        for (int j = 0; j < 4; j++) o[n][j] = 0.f;
#pragma unroll
    for (int j = 0; j < 4; j++) { mrow[j] = -1e30f; lrow[j] = 0.f; }

    const int skey = tid >> 3, sd = (tid & 7) * 8, sm = tid & 7;
    short8 kreg[4], vreg[4];
    // prologue: load tile 0 into regs
#pragma unroll
    for (int p = 0; p < 4; p++) {
        long off = base + (long)(p * 32 + skey) * 1536 + sd;
        kreg[p] = *(const short8*)&k[off];
        vreg[p] = *(const short8*)&v[off];
    }

    for (int s0 = 0; s0 < 4096; s0 += 128) {
        __syncthreads();   // prior tile's LDS reads done; prefetched regs landed (vmcnt drain)
        // stage regs -> LDS
#pragma unroll
        for (int p = 0; p < 4; p++) {
            int key = p * 32 + skey;
            *(short8*)&Ksm[key][sd] = kreg[p];
            int kc = key ^ (sm << 3);
#pragma unroll
            for (int i = 0; i < 8; i++) Vsm[sd + i][kc] = vreg[p][i];
        }
        __syncthreads();
        // prefetch next tile (latency hides under compute below)
        if (s0 + 128 < 4096) {
#pragma unroll
            for (int p = 0; p < 4; p++) {
                long off = base + (long)(s0 + 128 + p * 32 + skey) * 1536 + sd;
                kreg[p] = *(const short8*)&k[off];
                vreg[p] = *(const short8*)&v[off];
            }
        }

        // QK^T: 8 key-chunks x K=64
        f32x4 s[8];
#pragma unroll
        for (int c = 0; c < 8; c++) { s[c][0] = 0.f; s[c][1] = 0.f; s[c][2] = 0.f; s[c][3] = 0.f; }
        __builtin_amdgcn_s_setprio(1);
#pragma unroll
        for (int c = 0; c < 8; c++) {
            short8 kf0 = *(const short8*)&Ksm[c * 16 + lr][lg * 8];
            short8 kf1 = *(const short8*)&Ksm[c * 16 + lr][32 + lg * 8];
            s[c] = __builtin_amdgcn_mfma_f32_16x16x32_bf16(qf[0], kf0, s[c], 0, 0, 0);
            s[c] = __builtin_amdgcn_mfma_f32_16x16x32_bf16(qf[1], kf1, s[c], 0, 0, 0);
        }
        __builtin_amdgcn_s_setprio(0);

        // online softmax per q-row (row = lg*4+j; reduce over 16 lanes lr)
#pragma unroll
        for (int j = 0; j < 4; j++) {
            float mx = s[0][j];
#pragma unroll
            for (int c = 1; c < 8; c++) mx = fmaxf(mx, s[c][j]);
            mx = fmaxf(mx, __shfl_xor(mx, 1));
            mx = fmaxf(mx, __shfl_xor(mx, 2));
            mx = fmaxf(mx, __shfl_xor(mx, 4));
            mx = fmaxf(mx, __shfl_xor(mx, 8));
            float mn = fmaxf(mrow[j], mx);
            float alpha = __expf(mrow[j] - mn);
            mrow[j] = mn;
            float rs = 0.f;
#pragma unroll
            for (int c = 0; c < 8; c++) {
                float e = __expf(s[c][j] - mn);
                s[c][j] = e;
                rs += e;
            }
            rs += __shfl_xor(rs, 1);
            rs += __shfl_xor(rs, 2);
            rs += __shfl_xor(rs, 4);
            rs += __shfl_xor(rs, 8);
            lrow[j] = lrow[j] * alpha + rs;
#pragma unroll
            for (int n = 0; n < 4; n++) o[n][j] *= alpha;
        }

        // P: C-layout -> A-layout via per-wave LDS slice
#pragma unroll
        for (int c = 0; c < 8; c++)
#pragma unroll
            for (int j = 0; j < 4; j++)
                Psm[wid][lg * 4 + j][c * 16 + lr] = f2bf(s[c][j]);
        short8 pa[4];
#pragma unroll
        for (int kk = 0; kk < 4; kk++) pa[kk] = *(const short8*)&Psm[wid][lr][kk * 32 + lg * 8];

        __builtin_amdgcn_s_setprio(1);
#pragma unroll
        for (int n = 0; n < 4; n++) {
            const int vrow = n * 16 + lr;
            const int vsw = ((vrow >> 3) & 7) << 3;
#pragma unroll
            for (int kk = 0; kk < 4; kk++) {
                short8 vf = *(const short8*)&Vsm[vrow][(kk * 32 + lg * 8) ^ vsw];
                o[n] = __builtin_amdgcn_mfma_f32_16x16x32_bf16(pa[kk], vf, o[n], 0, 0, 0);
            }
        }
        __builtin_amdgcn_s_setprio(0);
    }

    const long obase = (long)b * 4096 * 512 + h * 64 + (long)(t0 + wid * 16) * 512;
#pragma unroll
    for (int n = 0; n < 4; n++)
#pragma unroll
        for (int j = 0; j < 4; j++)
            ctx[obase + (long)(lg * 4 + j) * 512 + n * 16 + lr] = f2bf(o[n][j] / lrow[j]);
}

// ---------------- Orchestration ----------------
extern "C" void kernel_launch(void* const* d_in, const int* in_sizes, int n_in,
                              void* d_out, int out_size, void* d_ws, size_t ws_size,
                              hipStream_t stream) {
    (void)in_sizes; (void)n_in; (void)out_size; (void)ws_size;
    const float* inputs = (const float*)d_in[0];
    const float* ln1_s  = (const float*)d_in[1];
    const float* ln1_o  = (const float*)d_in[2];
    const float* wq     = (const float*)d_in[3];
    const float* bq     = (const float*)d_in[4];
    const float* wk     = (const float*)d_in[5];
    const float* bk     = (const float*)d_in[6];
    const float* wv     = (const float*)d_in[7];
    const float* bv     = (const float*)d_in[8];
    const float* wo     = (const float*)d_in[9];
    const float* bo     = (const float*)d_in[10];
    const float* ln2_s  = (const float*)d_in[11];
    const float* ln2_o  = (const float*)d_in[12];
    const float* w1     = (const float*)d_in[13];
    const float* b1     = (const float*)d_in[14];
    const float* w2     = (const float*)d_in[15];
    const float* b2     = (const float*)d_in[16];
    float* out = (float*)d_out;

    char* p = (char*)d_ws;
    auto alloc = [&](size_t bytes) { void* r = (void*)p; p += (bytes + 255) & ~(size_t)255; return r; };
    short* x1    = (short*)alloc((size_t)8192 * 512 * 2);
    short* qkvb  = (short*)alloc((size_t)8192 * 1536 * 2);
    short* ctxb  = (short*)alloc((size_t)8192 * 512 * 2);
    short* yb    = (short*)alloc((size_t)8192 * 512 * 2);
    short* hb    = (short*)alloc((size_t)8192 * 2048 * 2);
    short* wqkvt = (short*)alloc((size_t)1536 * 512 * 2);
    short* wot   = (short*)alloc((size_t)512 * 512 * 2);
    short* w1t   = (short*)alloc((size_t)2048 * 512 * 2);
    short* w2t   = (short*)alloc((size_t)512 * 2048 * 2);
    float* bqkv  = (float*)alloc((size_t)1536 * 4);

    dim3 blk(256);
    // weights -> bf16 transposed; QKV weights concatenated into wqkvt[1536][512]
    wconv_t<<<dim3(8, 8), blk, 0, stream>>>(wq, wqkvt,                   512, 512);
    wconv_t<<<dim3(8, 8), blk, 0, stream>>>(wk, wqkvt + 512 * 512,       512, 512);
    wconv_t<<<dim3(8, 8), blk, 0, stream>>>(wv, wqkvt + 2 * 512 * 512,   512, 512);
    wconv_t<<<dim3(8, 8), blk, 0, stream>>>(wo, wot, 512, 512);
    wconv_t<<<dim3(8, 32), blk, 0, stream>>>(w1, w1t, 512, 2048);
    wconv_t<<<dim3(32, 8), blk, 0, stream>>>(w2, w2t, 2048, 512);
    hipMemcpyAsync(bqkv,        bq, 512 * sizeof(float), hipMemcpyDeviceToDevice, stream);
    hipMemcpyAsync(bqkv + 512,  bk, 512 * sizeof(float), hipMemcpyDeviceToDevice, stream);
    hipMemcpyAsync(bqkv + 1024, bv, 512 * sizeof(float), hipMemcpyDeviceToDevice, stream);

    // LN1
    ln_kernel<<<2048, blk, 0, stream>>>(inputs, ln1_s, ln1_o, x1);
    // fused QKV GEMM: [8192][512] @ [512][1536] -> [8192][1536]
    gemm_bt<false, true, false><<<dim3(64, 12), blk, 0, stream>>>(x1, wqkvt, bqkv, nullptr, qkvb, 8192, 1536, 512);
    // attention (q,k,v strided views into qkvb)
    attn_kernel<<<dim3(64, 16), blk, 0, stream>>>(qkvb, qkvb + 512, qkvb + 1024, ctxb);
    // out-proj + residual -> x (in d_out, fp32)
    gemm_bt<false, false, true><<<dim3(64, 4), blk, 0, stream>>>(ctxb, wot, bo, inputs, out, 8192, 512, 512);
    // LN2
    ln_kernel<<<2048, blk, 0, stream>>>(out, ln2_s, ln2_o, yb);
    // FFN1 + GELU
    gemm_bt<true, true, false><<<dim3(64, 16), blk, 0, stream>>>(yb, w1t, b1, nullptr, hb, 8192, 2048, 512);
    // FFN2 + residual -> out
    gemm_bt<false, false, true><<<dim3(64, 4), blk, 0, stream>>>(hb, w2t, b2, out, out, 8192, 512, 2048);
}

// Round 4
// 415.954 us; speedup vs baseline: 1.3610x; 1.0474x over previous
//
#include <hip/hip_runtime.h>
#include <hip/hip_bf16.h>

typedef __attribute__((ext_vector_type(4))) float f32x4;
typedef __attribute__((ext_vector_type(8))) short short8;

#define DEV __device__ __forceinline__

DEV short f2bf(float f) {
    union { float f; unsigned u; } a; a.f = f;
    unsigned r = a.u + 0x7fffu + ((a.u >> 16) & 1u);
    return (short)(r >> 16);
}

DEV float bf2f(short s) {
    union { unsigned u; float f; } a;
    a.u = ((unsigned)(unsigned short)s) << 16;
    return a.f;
}

// packed f32x2 -> bf16x2 (low = a, high = b), RTNE in HW
DEV unsigned cvt_pk_bf16(float a, float b) {
    unsigned r;
    asm("v_cvt_pk_bf16_f32 %0, %1, %2" : "=v"(r) : "v"(a), "v"(b));
    return r;
}

DEV float exp2_fast(float x) { return __builtin_amdgcn_exp2f(x); }

DEV float gelu_f(float x) {
    float u = 0.7978845608028654f * (x + 0.044715f * x * x * x);
    float e = __expf(2.0f * u);
    float t = 1.0f - 2.0f / (e + 1.0f);   // tanh(u)
    return 0.5f * x * (1.0f + t);
}

// ---------------- LayerNorm: fp32 in -> bf16 out, D=512, wave per row ----------------
__global__ __launch_bounds__(256) void ln_kernel(const float* __restrict__ x,
                                                 const float* __restrict__ scale,
                                                 const float* __restrict__ offset,
                                                 short* __restrict__ out) {
    const int wid = threadIdx.x >> 6, lane = threadIdx.x & 63;
    const long row = (long)blockIdx.x * 4 + wid;
    const float* xr = x + row * 512;
    f32x4 v0 = *(const f32x4*)&xr[lane * 8];
    f32x4 v1 = *(const f32x4*)&xr[lane * 8 + 4];
    float s = 0.f, sq = 0.f;
#pragma unroll
    for (int i = 0; i < 4; i++) {
        s += v0[i] + v1[i];
        sq += v0[i] * v0[i] + v1[i] * v1[i];
    }
#pragma unroll
    for (int m = 1; m < 64; m <<= 1) { s += __shfl_xor(s, m); sq += __shfl_xor(sq, m); }
    float mean = s * (1.0f / 512.0f);
    float var = sq * (1.0f / 512.0f) - mean * mean;
    float inv = rsqrtf(var + 1e-5f);
    f32x4 sc0 = *(const f32x4*)&scale[lane * 8];
    f32x4 sc1 = *(const f32x4*)&scale[lane * 8 + 4];
    f32x4 of0 = *(const f32x4*)&offset[lane * 8];
    f32x4 of1 = *(const f32x4*)&offset[lane * 8 + 4];
    short8 o;
#pragma unroll
    for (int i = 0; i < 4; i++) {
        o[i]     = f2bf((v0[i] - mean) * inv * sc0[i] + of0[i]);
        o[4 + i] = f2bf((v1[i] - mean) * inv * sc1[i] + of1[i]);
    }
    *(short8*)&out[row * 512 + lane * 8] = o;
}

// ---------------- Fused weight prep: 6 transposes + bias concat in ONE launch ----------------
// Tiles 0..255: wq/wk/wv/wo (8x8 each); 256..511: w1 (8x32); 512..767: w2 (32x8); 768: bias concat.
__global__ __launch_bounds__(256) void prep_kernel(const float* __restrict__ wq,
                                                   const float* __restrict__ wk,
                                                   const float* __restrict__ wv,
                                                   const float* __restrict__ wo,
                                                   const float* __restrict__ w1,
                                                   const float* __restrict__ w2,
                                                   const float* __restrict__ bq,
                                                   const float* __restrict__ bk,
                                                   const float* __restrict__ bv,
                                                   short* __restrict__ wqkvt,
                                                   short* __restrict__ wot,
                                                   short* __restrict__ w1t,
                                                   short* __restrict__ w2t,
                                                   float* __restrict__ bqkv) {
    const int bid = blockIdx.x;
    if (bid == 768) {
        for (int i = threadIdx.x; i < 512; i += 256) {
            bqkv[i] = bq[i]; bqkv[512 + i] = bk[i]; bqkv[1024 + i] = bv[i];
        }
        return;
    }
    const float* src; short* dst; int Kd, N, kt, nt;
    if (bid < 256) {
        Kd = 512; N = 512;
        const int which = bid >> 6, local = bid & 63;
        kt = local & 7; nt = local >> 3;
        if (which == 0)      { src = wq; dst = wqkvt; }
        else if (which == 1) { src = wk; dst = wqkvt + 512 * 512; }
        else if (which == 2) { src = wv; dst = wqkvt + 2 * 512 * 512; }
        else                 { src = wo; dst = wot; }
    } else if (bid < 512) {
        src = w1; dst = w1t; Kd = 512; N = 2048;
        const int local = bid - 256; kt = local & 7; nt = local >> 3;
    } else {
        src = w2; dst = w2t; Kd = 2048; N = 512;
        const int local = bid - 512; kt = local & 31; nt = local >> 5;
    }
    __shared__ float tile[64][65];
    const int k0 = kt * 64, n0 = nt * 64;
    const int tid = threadIdx.x;
#pragma unroll
    for (int ld = 0; ld < 4; ld++) {
        int li = ld * 1024 + tid * 4;
        int r = li >> 6, c = li & 63;
        f32x4 tv = *(const f32x4*)&src[(long)(k0 + r) * N + n0 + c];
        tile[r][c] = tv[0]; tile[r][c + 1] = tv[1];
        tile[r][c + 2] = tv[2]; tile[r][c + 3] = tv[3];
    }
    __syncthreads();
#pragma unroll
    for (int st = 0; st < 2; st++) {
        int li = st * 2048 + tid * 8;
        int r = li >> 6, c = li & 63;
        short8 o;
#pragma unroll
        for (int i = 0; i < 8; i++) o[i] = f2bf(tile[c + i][r]);
        *(short8*)&dst[(long)(n0 + r) * Kd + k0 + c] = o;
    }
}

// ---------------- GEMM: C[M][N] = A[M][Kd] @ Bt[N][Kd]^T + bias (+gelu)(+resid) ----------------
template <bool GELU_ACT, bool OUT_BF16, bool RESID>
__global__ __launch_bounds__(256) void gemm_bt(const short* __restrict__ A,
                                               const short* __restrict__ Bt,
                                               const float* __restrict__ bias,
                                               const float* __restrict__ resid,
                                               void* __restrict__ Cout,
                                               int M, int N, int Kd) {
    __shared__ short Asm[128][72];
    __shared__ short Bsm[128][72];
    const int tid = threadIdx.x;
    const int wid = tid >> 6, lane = tid & 63;
    const int lr = lane & 15, lg = lane >> 4;
    const int row0 = blockIdx.x * 128, col0 = blockIdx.y * 128;
    const int wm = (wid >> 1) * 64, wn = (wid & 1) * 64;

    f32x4 acc[4][4];
#pragma unroll
    for (int m = 0; m < 4; m++)
#pragma unroll
        for (int n = 0; n < 4; n++)
#pragma unroll
            for (int j = 0; j < 4; j++) acc[m][n][j] = 0.f;

    for (int k0 = 0; k0 < Kd; k0 += 64) {
#pragma unroll
        for (int ld = 0; ld < 4; ld++) {
            int li = ld * 2048 + tid * 8;
            int r = li >> 6, c = li & 63;
            *(short8*)&Asm[r][c] = *(const short8*)&A[(long)(row0 + r) * Kd + k0 + c];
            *(short8*)&Bsm[r][c] = *(const short8*)&Bt[(long)(col0 + r) * Kd + k0 + c];
        }
        __syncthreads();
#pragma unroll
        for (int kk = 0; kk < 64; kk += 32) {
            short8 af[4], bf[4];
#pragma unroll
            for (int m = 0; m < 4; m++) af[m] = *(const short8*)&Asm[wm + m * 16 + lr][kk + lg * 8];
#pragma unroll
            for (int n = 0; n < 4; n++) bf[n] = *(const short8*)&Bsm[wn + n * 16 + lr][kk + lg * 8];
#pragma unroll
            for (int m = 0; m < 4; m++)
#pragma unroll
                for (int n = 0; n < 4; n++)
                    acc[m][n] = __builtin_amdgcn_mfma_f32_16x16x32_bf16(af[m], bf[n], acc[m][n], 0, 0, 0);
        }
        __syncthreads();
    }

#pragma unroll
    for (int m = 0; m < 4; m++) {
#pragma unroll
        for (int n = 0; n < 4; n++) {
#pragma unroll
            for (int j = 0; j < 4; j++) {
                int r = row0 + wm + m * 16 + lg * 4 + j;
                int c = col0 + wn + n * 16 + lr;
                float v = acc[m][n][j] + bias[c];
                if constexpr (GELU_ACT) v = gelu_f(v);
                if constexpr (RESID) v += resid[(long)r * N + c];
                if constexpr (OUT_BF16) ((short*)Cout)[(long)r * N + c] = f2bf(v);
                else                    ((float*)Cout)[(long)r * N + c] = v;
            }
        }
    }
}

// ---------------- Flash attention v3 ----------------
// QBLK=128 (4 waves x 32 q-rows as 2 row-groups of 16), KVBLK=128.
// exp2-domain softmax (Q pre-scaled by 0.125*log2e), defer-max THR=8 (log2),
// cvt_pk P->bf16, Psm reused per row-group (LDS 53KB -> 3 blocks/CU).
__global__ __launch_bounds__(256) void attn_kernel(const short* __restrict__ q,
                                                   const short* __restrict__ k,
                                                   const short* __restrict__ v,
                                                   short* __restrict__ ctx) {
    __shared__ short Ksm[128][72];       // [key][d]
    __shared__ short Vsm[64][136];       // [d][key^swz]
    __shared__ short Psm[4][16][136];    // per-wave P staging, reused per row-group
    const int tid = threadIdx.x, wid = tid >> 6, lane = tid & 63;
    const int lr = lane & 15, lg = lane >> 4;
    const int bh = blockIdx.y, b = bh >> 3, h = bh & 7;
    const int t0 = blockIdx.x * 128;
    const long base = (long)b * 4096 * 1536 + h * 64;

    // Q frags, pre-scaled by 0.125 * log2(e) (moves softmax into exp2 domain)
    short8 qf[2][2];
#pragma unroll
    for (int rg = 0; rg < 2; rg++) {
        const long qoff = base + (long)(t0 + wid * 32 + rg * 16 + lr) * 1536 + lg * 8;
        short8 q0 = *(const short8*)&q[qoff];
        short8 q1 = *(const short8*)&q[qoff + 32];
#pragma unroll
        for (int i = 0; i < 8; i++) {
            qf[rg][0][i] = f2bf(bf2f(q0[i]) * 0.18033688f);
            qf[rg][1][i] = f2bf(bf2f(q1[i]) * 0.18033688f);
        }
    }

    f32x4 o[2][4];            // [rg][n]
    float mrow[8], lrow[8];   // [rg*4+j]
#pragma unroll
    for (int rg = 0; rg < 2; rg++)
#pragma unroll
        for (int n = 0; n < 4; n++)
#pragma unroll
            for (int j = 0; j < 4; j++) o[rg][n][j] = 0.f;
#pragma unroll
    for (int j = 0; j < 8; j++) { mrow[j] = -1e30f; lrow[j] = 0.f; }

    const int skey = tid >> 3, sd = (tid & 7) * 8, sm = tid & 7;
    short8 kreg[4], vreg[4];
#pragma unroll
    for (int p = 0; p < 4; p++) {
        long off = base + (long)(p * 32 + skey) * 1536 + sd;
        kreg[p] = *(const short8*)&k[off];
        vreg[p] = *(const short8*)&v[off];
    }

    for (int s0 = 0; s0 < 4096; s0 += 128) {
        __syncthreads();   // prior tile's LDS reads done
        // stage regs -> LDS (K row-major; V transposed + XOR swizzle, conflict-free)
#pragma unroll
        for (int p = 0; p < 4; p++) {
            int key = p * 32 + skey;
            *(short8*)&Ksm[key][sd] = kreg[p];
            int kc = key ^ (sm << 3);
#pragma unroll
            for (int i = 0; i < 8; i++) Vsm[sd + i][kc] = vreg[p][i];
        }
        __syncthreads();
        // prefetch next tile (hides under the 2-row-group compute below)
        if (s0 + 128 < 4096) {
#pragma unroll
            for (int p = 0; p < 4; p++) {
                long off = base + (long)(s0 + 128 + p * 32 + skey) * 1536 + sd;
                kreg[p] = *(const short8*)&k[off];
                vreg[p] = *(const short8*)&v[off];
            }
        }

#pragma unroll
        for (int rg = 0; rg < 2; rg++) {
            // QK^T (log2-domain scores)
            f32x4 s[8];
#pragma unroll
            for (int c = 0; c < 8; c++) { s[c][0] = 0.f; s[c][1] = 0.f; s[c][2] = 0.f; s[c][3] = 0.f; }
            __builtin_amdgcn_s_setprio(1);
#pragma unroll
            for (int c = 0; c < 8; c++) {
                short8 kf0 = *(const short8*)&Ksm[c * 16 + lr][lg * 8];
                short8 kf1 = *(const short8*)&Ksm[c * 16 + lr][32 + lg * 8];
                s[c] = __builtin_amdgcn_mfma_f32_16x16x32_bf16(qf[rg][0], kf0, s[c], 0, 0, 0);
                s[c] = __builtin_amdgcn_mfma_f32_16x16x32_bf16(qf[rg][1], kf1, s[c], 0, 0, 0);
            }
            __builtin_amdgcn_s_setprio(0);

            // online softmax, exp2 domain, defer-max (THR=8 -> P <= 256, bf16-safe)
#pragma unroll
            for (int j = 0; j < 4; j++) {
                const int r8 = rg * 4 + j;
                float m01 = fmaxf(s[0][j], s[1][j]), m23 = fmaxf(s[2][j], s[3][j]);
                float m45 = fmaxf(s[4][j], s[5][j]), m67 = fmaxf(s[6][j], s[7][j]);
                float mx = fmaxf(fmaxf(m01, m23), fmaxf(m45, m67));
                mx = fmaxf(mx, __shfl_xor(mx, 1));
                mx = fmaxf(mx, __shfl_xor(mx, 2));
                mx = fmaxf(mx, __shfl_xor(mx, 4));
                mx = fmaxf(mx, __shfl_xor(mx, 8));
                float mn = mrow[r8];
                if (!__all(mx <= mn + 8.0f)) {
                    mn = fmaxf(mrow[r8], mx);
                    float alpha = exp2_fast(mrow[r8] - mn);
                    mrow[r8] = mn;
                    lrow[r8] *= alpha;
#pragma unroll
                    for (int n = 0; n < 4; n++) o[rg][n][j] *= alpha;
                }
                float rs = 0.f;
#pragma unroll
                for (int c = 0; c < 8; c++) {
                    float e = exp2_fast(s[c][j] - mn);
                    s[c][j] = e;
                    rs += e;
                }
                rs += __shfl_xor(rs, 1);
                rs += __shfl_xor(rs, 2);
                rs += __shfl_xor(rs, 4);
                rs += __shfl_xor(rs, 8);
                lrow[r8] += rs;
            }

            // stage P (packed bf16 convert), wave-private slice
#pragma unroll
            for (int j = 0; j < 4; j++) {
                short* prow = &Psm[wid][lg * 4 + j][lr];
#pragma unroll
                for (int c = 0; c < 8; c += 2) {
                    unsigned pk = cvt_pk_bf16(s[c][j], s[c + 1][j]);
                    prow[c * 16]      = (short)(pk & 0xffff);
                    prow[c * 16 + 16] = (short)(pk >> 16);
                }
            }
            short8 pa[4];
#pragma unroll
            for (int kk = 0; kk < 4; kk++) pa[kk] = *(const short8*)&Psm[wid][lr][kk * 32 + lg * 8];

            __builtin_amdgcn_s_setprio(1);
#pragma unroll
            for (int n = 0; n < 4; n++) {
                const int vrow = n * 16 + lr;
                const int vsw = ((vrow >> 3) & 7) << 3;
#pragma unroll
                for (int kk = 0; kk < 4; kk++) {
                    short8 vf = *(const short8*)&Vsm[vrow][(kk * 32 + lg * 8) ^ vsw];
                    o[rg][n] = __builtin_amdgcn_mfma_f32_16x16x32_bf16(pa[kk], vf, o[rg][n], 0, 0, 0);
                }
            }
            __builtin_amdgcn_s_setprio(0);
        }
    }

    const long cb = (long)b * 4096 * 512 + h * 64 + (long)(t0 + wid * 32) * 512;
#pragma unroll
    for (int rg = 0; rg < 2; rg++)
#pragma unroll
        for (int j = 0; j < 4; j++) {
            float il = 1.0f / lrow[rg * 4 + j];
#pragma unroll
            for (int n = 0; n < 4; n++)
                ctx[cb + (long)(rg * 16 + lg * 4 + j) * 512 + n * 16 + lr] = f2bf(o[rg][n][j] * il);
        }
}

// ---------------- Orchestration ----------------
extern "C" void kernel_launch(void* const* d_in, const int* in_sizes, int n_in,
                              void* d_out, int out_size, void* d_ws, size_t ws_size,
                              hipStream_t stream) {
    (void)in_sizes; (void)n_in; (void)out_size; (void)ws_size;
    const float* inputs = (const float*)d_in[0];
    const float* ln1_s  = (const float*)d_in[1];
    const float* ln1_o  = (const float*)d_in[2];
    const float* wq     = (const float*)d_in[3];
    const float* bq     = (const float*)d_in[4];
    const float* wk     = (const float*)d_in[5];
    const float* bk     = (const float*)d_in[6];
    const float* wv     = (const float*)d_in[7];
    const float* bv     = (const float*)d_in[8];
    const float* wo     = (const float*)d_in[9];
    const float* bo     = (const float*)d_in[10];
    const float* ln2_s  = (const float*)d_in[11];
    const float* ln2_o  = (const float*)d_in[12];
    const float* w1     = (const float*)d_in[13];
    const float* b1     = (const float*)d_in[14];
    const float* w2     = (const float*)d_in[15];
    const float* b2     = (const float*)d_in[16];
    float* out = (float*)d_out;

    char* p = (char*)d_ws;
    auto alloc = [&](size_t bytes) { void* r = (void*)p; p += (bytes + 255) & ~(size_t)255; return r; };
    short* x1    = (short*)alloc((size_t)8192 * 512 * 2);
    short* qkvb  = (short*)alloc((size_t)8192 * 1536 * 2);
    short* ctxb  = (short*)alloc((size_t)8192 * 512 * 2);
    short* yb    = (short*)alloc((size_t)8192 * 512 * 2);
    short* hb    = (short*)alloc((size_t)8192 * 2048 * 2);
    short* wqkvt = (short*)alloc((size_t)1536 * 512 * 2);
    short* wot   = (short*)alloc((size_t)512 * 512 * 2);
    short* w1t   = (short*)alloc((size_t)2048 * 512 * 2);
    short* w2t   = (short*)alloc((size_t)512 * 2048 * 2);
    float* bqkv  = (float*)alloc((size_t)1536 * 4);

    dim3 blk(256);
    // all weight transposes + bias concat in one launch
    prep_kernel<<<769, blk, 0, stream>>>(wq, wk, wv, wo, w1, w2, bq, bk, bv,
                                         wqkvt, wot, w1t, w2t, bqkv);
    // LN1
    ln_kernel<<<2048, blk, 0, stream>>>(inputs, ln1_s, ln1_o, x1);
    // fused QKV GEMM: [8192][512] @ [512][1536] -> [8192][1536]
    gemm_bt<false, true, false><<<dim3(64, 12), blk, 0, stream>>>(x1, wqkvt, bqkv, nullptr, qkvb, 8192, 1536, 512);
    // attention (q,k,v strided views into qkvb)
    attn_kernel<<<dim3(32, 16), blk, 0, stream>>>(qkvb, qkvb + 512, qkvb + 1024, ctxb);
    // out-proj + residual -> x (in d_out, fp32)
    gemm_bt<false, false, true><<<dim3(64, 4), blk, 0, stream>>>(ctxb, wot, bo, inputs, out, 8192, 512, 512);
    // LN2
    ln_kernel<<<2048, blk, 0, stream>>>(out, ln2_s, ln2_o, yb);
    // FFN1 + GELU
    gemm_bt<true, true, false><<<dim3(64, 16), blk, 0, stream>>>(yb, w1t, b1, nullptr, hb, 8192, 2048, 512);
    // FFN2 + residual -> out
    gemm_bt<false, false, true><<<dim3(64, 4), blk, 0, stream>>>(hb, w2t, b2, out, out, 8192, 512, 2048);
}